// Round 2
// baseline (617.275 us; speedup 1.0000x reference)
//
#include <hip/hip_runtime.h>
#include <hip/hip_bf16.h>

typedef __attribute__((ext_vector_type(4))) float f32x4;
typedef __attribute__((ext_vector_type(8))) short bf16x8;
typedef __attribute__((ext_vector_type(4))) int   i32x4;

#define S_LEN 1024
#define DQ    64
#define KT    128
#define NKVT  8
#define VSTR  138   // Vt row stride in shorts (69 dwords, odd -> conflict-free frag reads)
#define CSTR  68    // Cx row stride in floats (16B-aligned rows)

__device__ __forceinline__ unsigned short bf16u(float x) {
    union { float f; unsigned u; } v; v.f = x;
    return (unsigned short)((v.u + 0x7fffu + ((v.u >> 16) & 1u)) >> 16);
}

// fragment: elems {0..3} at p, {4..7} at p+16 shorts; 4B-aligned safe (ds_read2_b32)
__device__ __forceinline__ bf16x8 ld_frag2(const unsigned short* p) {
    union { bf16x8 v; unsigned u[4]; } r;
    r.u[0] = *(const unsigned*)(p);
    r.u[1] = *(const unsigned*)(p + 2);
    r.u[2] = *(const unsigned*)(p + 16);
    r.u[3] = *(const unsigned*)(p + 18);
    return r.v;
}

__device__ __forceinline__ bf16x8 pack8(float4 a, float4 b) {
    union { bf16x8 v; unsigned short e[8]; } u;
    u.e[0] = bf16u(a.x); u.e[1] = bf16u(a.y); u.e[2] = bf16u(a.z); u.e[3] = bf16u(a.w);
    u.e[4] = bf16u(b.x); u.e[5] = bf16u(b.y); u.e[6] = bf16u(b.z); u.e[7] = bf16u(b.w);
    return u.v;
}

__global__ __launch_bounds__(512) void attn_fused(
    const float* __restrict__ Qg, const float* __restrict__ Kg,
    const float* __restrict__ Vg, const int* __restrict__ Mg,
    float* __restrict__ Og, float* __restrict__ Ag)
{
    const int tid  = threadIdx.x;
    const int lane = tid & 63;
    const int wid  = tid >> 6;
    const int l15  = lane & 15;
    const int lg   = lane >> 4;   // 0..3
    const int wr   = wid >> 2;    // 0..1  q half
    const int wc   = wid & 3;     // 0..3  k quarter-strip

    const int bid = blockIdx.x;
    const int bh  = bid >> 5;
    const int qt  = bid & 31;
    const int b   = bh >> 4;

    const size_t kvbase = (size_t)bh * (S_LEN * DQ);
    const float* Qp = Qg + kvbase + (size_t)qt * (32 * DQ);
    const float* Kp = Kg + kvbase;
    const float* Vp = Vg + kvbase;
    const int*   Mp = Mg + (size_t)b * (size_t)(S_LEN * S_LEN) + (size_t)(qt * 32) * S_LEN;
    float*       Ap = Ag + (size_t)bh * (size_t)(S_LEN * S_LEN) + (size_t)(qt * 32) * S_LEN;
    float*       Op = Og + kvbase + (size_t)qt * (32 * DQ);

    // one shared buffer, phase-aliased: red(softmax) | Vt(phase2) | Cx(reduce)
    __shared__ __align__(16) unsigned char smem[DQ * VSTR * 2];  // 17664 B
    unsigned short* Vt  = (unsigned short*)smem;
    float*          Cx  = (float*)smem;
    float*          red = (float*)smem;

    // ---- Q fragments direct from global (B-operand: row = q = l15) ----
    bf16x8 aq0, aq1;
    {
        const float* qrow = Qp + (size_t)(wr * 16 + l15) * DQ + lg * 4;
        aq0 = pack8(*(const float4*)(qrow),      *(const float4*)(qrow + 16));
        aq1 = pack8(*(const float4*)(qrow + 32), *(const float4*)(qrow + 48));
    }

    // sc[t][r] = S[q = wr*16+l15][k = (t>>1)*128 + wc*32 + (t&1)*16 + lg*4 + r]
    f32x4 sc[16];
#pragma unroll
    for (int t = 0; t < 16; ++t) sc[t] = (f32x4){0.f, 0.f, 0.f, 0.f};

    // ---- Phase 1: scores = K·Q^T (swapped operands), K direct from global ----
#pragma unroll
    for (int kvt = 0; kvt < NKVT; ++kvt) {
#pragma unroll
        for (int ct = 0; ct < 2; ++ct) {
            const float* krow = Kp + (size_t)(kvt * 128 + wc * 32 + ct * 16 + l15) * DQ + lg * 4;
            bf16x8 k0 = pack8(*(const float4*)(krow),      *(const float4*)(krow + 16));
            bf16x8 k1 = pack8(*(const float4*)(krow + 32), *(const float4*)(krow + 48));
            f32x4 acc = sc[kvt * 2 + ct];
            acc = __builtin_amdgcn_mfma_f32_16x16x32_bf16(k0, aq0, acc, 0, 0, 0);
            acc = __builtin_amdgcn_mfma_f32_16x16x32_bf16(k1, aq1, acc, 0, 0, 0);
            sc[kvt * 2 + ct] = acc;
        }
    }

    // ---- scale + mask (vectorized int4 loads) ----
    const int* mrow = Mp + (size_t)(wr * 16 + l15) * S_LEN + wc * 32 + lg * 4;
#pragma unroll
    for (int t = 0; t < 16; ++t) {
        const i32x4 m4 = *(const i32x4*)(mrow + (t >> 1) * 128 + (t & 1) * 16);
#pragma unroll
        for (int r = 0; r < 4; ++r)
            sc[t][r] = m4[r] ? 1e-9f : sc[t][r] * 0.125f;
    }

    // ---- row max: thread-local (one q row per thread) + shfl + cross-wave LDS ----
    float rmax = sc[0][0];
#pragma unroll
    for (int t = 0; t < 16; ++t)
#pragma unroll
        for (int r = 0; r < 4; ++r) rmax = fmaxf(rmax, sc[t][r]);
    rmax = fmaxf(rmax, __shfl_xor(rmax, 16));
    rmax = fmaxf(rmax, __shfl_xor(rmax, 32));
    __syncthreads();                       // phase-1 done everywhere; red safe to use
    if (lane < 16) red[(wr * 16 + l15) * 4 + wc] = rmax;
    __syncthreads();
    {
        const f32x4 q4 = *(const f32x4*)(red + (wr * 16 + l15) * 4);
        rmax = fmaxf(fmaxf(q4[0], q4[1]), fmaxf(q4[2], q4[3]));
    }

    // ---- exp + row sum ----
    float rsum = 0.f;
#pragma unroll
    for (int t = 0; t < 16; ++t)
#pragma unroll
        for (int r = 0; r < 4; ++r) {
            const float p = __expf(sc[t][r] - rmax);
            sc[t][r] = p;
            rsum += p;
        }
    rsum += __shfl_xor(rsum, 16);
    rsum += __shfl_xor(rsum, 32);
    __syncthreads();                       // all reads of red(max) done
    if (lane < 16) red[(wr * 16 + l15) * 4 + wc] = rsum;
    __syncthreads();
    float rinv;
    {
        const f32x4 q4 = *(const f32x4*)(red + (wr * 16 + l15) * 4);
        rinv = 1.0f / (q4[0] + q4[1] + q4[2] + q4[3]);
    }
#pragma unroll
    for (int t = 0; t < 16; ++t)
#pragma unroll
        for (int r = 0; r < 4; ++r) sc[t][r] *= rinv;

    // ---- attn output: float4 stores (4 consecutive k per lane) ----
    float* arow = Ap + (size_t)(wr * 16 + l15) * S_LEN + wc * 32 + lg * 4;
#pragma unroll
    for (int t = 0; t < 16; ++t)
        *(f32x4*)(arow + (t >> 1) * 128 + (t & 1) * 16) = sc[t];

    // ---- Phase 2: context = P·V; P already in A-fragment layout in registers ----
    f32x4 co[4];
#pragma unroll
    for (int m = 0; m < 4; ++m) co[m] = (f32x4){0.f, 0.f, 0.f, 0.f};

    for (int kvt = 0; kvt < NKVT; ++kvt) {
        __syncthreads();   // prior iter's Vt reads (and red reads, iter 0) complete
        const float* vsrc = Vp + (size_t)kvt * (KT * DQ);
#pragma unroll
        for (int i = 0; i < 4; ++i) {
            const int f = (i * 512 + tid) * 4;
            const float4 v4 = *(const float4*)(vsrc + f);
            const int kr = f >> 6, dc = f & 63;
            Vt[(dc + 0) * VSTR + kr] = bf16u(v4.x);
            Vt[(dc + 1) * VSTR + kr] = bf16u(v4.y);
            Vt[(dc + 2) * VSTR + kr] = bf16u(v4.z);
            Vt[(dc + 3) * VSTR + kr] = bf16u(v4.w);
        }
        __syncthreads();
        // P fragment in-register: elems 0..3 = sc[2kvt] (k_local 0..15), 4..7 = sc[2kvt+1]
        union { bf16x8 v; unsigned short e[8]; } pa;
#pragma unroll
        for (int r = 0; r < 4; ++r) {
            pa.e[r]     = bf16u(sc[kvt * 2 + 0][r]);
            pa.e[4 + r] = bf16u(sc[kvt * 2 + 1][r]);
        }
#pragma unroll
        for (int m = 0; m < 4; ++m) {
            const bf16x8 bv = ld_frag2(Vt + (size_t)(m * 16 + l15) * VSTR + wc * 32 + lg * 4);
            co[m] = __builtin_amdgcn_mfma_f32_16x16x32_bf16(pa.v, bv, co[m], 0, 0, 0);
        }
    }

    // ---- deterministic ordered cross-wave reduce of context into Cx ----
    __syncthreads();   // last Vt reads complete before Cx (aliased) writes
#pragma unroll
    for (int w = 0; w < 4; ++w) {
        if (wc == w) {
#pragma unroll
            for (int m = 0; m < 4; ++m)
#pragma unroll
                for (int r = 0; r < 4; ++r) {
                    float* p = Cx + (size_t)(wr * 16 + lg * 4 + r) * CSTR + m * 16 + l15;
                    if (w == 0) *p = co[m][r];
                    else        *p += co[m][r];
                }
        }
        __syncthreads();
    }

    // ---- coalesced context write ----
    {
        const int row = tid >> 4, col = (tid & 15) * 4;
        const f32x4 o = *(const f32x4*)(Cx + (size_t)row * CSTR + col);
        *(f32x4*)(Op + (size_t)row * DQ + col) = o;
    }
}

extern "C" void kernel_launch(void* const* d_in, const int* in_sizes, int n_in,
                              void* d_out, int out_size, void* d_ws, size_t ws_size,
                              hipStream_t stream) {
    const float* Q = (const float*)d_in[0];
    const float* K = (const float*)d_in[1];
    const float* V = (const float*)d_in[2];
    const int*   M = (const int*)d_in[3];
    float* ctx  = (float*)d_out;
    float* attn = ctx + (size_t)8 * 16 * 1024 * 64;   // context first, then attn
    attn_fused<<<dim3(4096), dim3(512), 0, stream>>>(Q, K, V, M, ctx, attn);
}

// Round 3
// 490.864 us; speedup vs baseline: 1.2575x; 1.2575x over previous
//
#include <hip/hip_runtime.h>
#include <hip/hip_bf16.h>

typedef __attribute__((ext_vector_type(4))) float f32x4;
typedef __attribute__((ext_vector_type(8))) short bf16x8;
typedef __attribute__((ext_vector_type(4))) int   i32x4;

#define S_LEN 1024
#define DQ    64
#define VSTR  266   // Vt row stride in shorts; 2*266 % 32 == 20 -> conflict-benign
#define CSTR  68    // Cx row stride in floats

__device__ __forceinline__ unsigned short bf16u(float x) {
    union { float f; unsigned u; } v; v.f = x;
    return (unsigned short)((v.u + 0x7fffu + ((v.u >> 16) & 1u)) >> 16);
}

// fragment: elems {0..3} at p, {4..7} at p+16 shorts (4B-aligned dword pairs)
__device__ __forceinline__ bf16x8 ld_frag2(const unsigned short* p) {
    union { bf16x8 v; unsigned u[4]; } r;
    r.u[0] = *(const unsigned*)(p);
    r.u[1] = *(const unsigned*)(p + 2);
    r.u[2] = *(const unsigned*)(p + 16);
    r.u[3] = *(const unsigned*)(p + 18);
    return r.v;
}

__device__ __forceinline__ bf16x8 pack8(float4 a, float4 b) {
    union { bf16x8 v; unsigned short e[8]; } u;
    u.e[0] = bf16u(a.x); u.e[1] = bf16u(a.y); u.e[2] = bf16u(a.z); u.e[3] = bf16u(a.w);
    u.e[4] = bf16u(b.x); u.e[5] = bf16u(b.y); u.e[6] = bf16u(b.z); u.e[7] = bf16u(b.w);
    return u.v;
}

__global__ __launch_bounds__(1024, 8) void attn_fused(
    const float* __restrict__ Qg, const float* __restrict__ Kg,
    const float* __restrict__ Vg, const int* __restrict__ Mg,
    float* __restrict__ Og, float* __restrict__ Ag)
{
    const int tid  = threadIdx.x;
    const int lane = tid & 63;
    const int wid  = tid >> 6;     // 0..15
    const int l15  = lane & 15;
    const int lg   = lane >> 4;    // 0..3
    const int wc   = wid >> 1;     // 0..7  (k strip)
    const int wr   = wid & 1;      // 0..1  (q half)

    const int bid = blockIdx.x;
    const int bh  = bid >> 5;
    const int qt  = bid & 31;
    const int b   = bh >> 4;

    const size_t kvbase = (size_t)bh * (S_LEN * DQ);
    const float* Qp = Qg + kvbase + (size_t)qt * (32 * DQ);
    const float* Kp = Kg + kvbase;
    const float* Vp = Vg + kvbase;
    const int*   Mp = Mg + (size_t)b * (size_t)(S_LEN * S_LEN) + (size_t)(qt * 32) * S_LEN;
    float*       Ap = Ag + (size_t)bh * (size_t)(S_LEN * S_LEN) + (size_t)(qt * 32) * S_LEN;
    float*       Op = Og + kvbase + (size_t)qt * (32 * DQ);

    // phase-aliased shared: red(softmax) | Vt(phase2) | Cx(reduce)
    __shared__ __align__(16) unsigned char smem[DQ * VSTR * 2];  // 34048 B
    unsigned short* Vt  = (unsigned short*)smem;
    float*          red = (float*)smem;
    float*          Cx  = (float*)smem;

    const int qrow = wr * 16 + l15;

    // ---- mask prefetch -> 32 bits (loads overlap phase-1 MFMAs) ----
    unsigned mbits = 0;
    {
        const int* mrow = Mp + (size_t)qrow * S_LEN + wc * 32 + lg * 4;
#pragma unroll
        for (int i = 0; i < 4; ++i)
#pragma unroll
            for (int h = 0; h < 2; ++h) {
                const i32x4 m4 = *(const i32x4*)(mrow + i * 256 + h * 16);
#pragma unroll
                for (int r = 0; r < 4; ++r)
                    mbits |= (m4[r] ? 1u : 0u) << ((i * 2 + h) * 4 + r);
            }
    }

    // ---- Q fragments direct from global (B-operand: row = q = l15) ----
    bf16x8 aq0, aq1;
    {
        const float* qr = Qp + (size_t)qrow * DQ + lg * 4;
        aq0 = pack8(*(const float4*)(qr),      *(const float4*)(qr + 16));
        aq1 = pack8(*(const float4*)(qr + 32), *(const float4*)(qr + 48));
    }

    // sc[2i+h][r] = S[q=qrow][k = i*256 + wc*32 + h*16 + lg*4 + r]
    f32x4 sc[8];
#pragma unroll
    for (int t = 0; t < 8; ++t) sc[t] = (f32x4){0.f, 0.f, 0.f, 0.f};

    // ---- Phase 1: scores = K·Q^T (swapped), K direct from global ----
#pragma unroll
    for (int i = 0; i < 4; ++i)
#pragma unroll
        for (int h = 0; h < 2; ++h) {
            const float* krow = Kp + (size_t)(i * 256 + wc * 32 + h * 16 + l15) * DQ + lg * 4;
            bf16x8 k0 = pack8(*(const float4*)(krow),      *(const float4*)(krow + 16));
            bf16x8 k1 = pack8(*(const float4*)(krow + 32), *(const float4*)(krow + 48));
            f32x4 acc = sc[i * 2 + h];
            acc = __builtin_amdgcn_mfma_f32_16x16x32_bf16(k0, aq0, acc, 0, 0, 0);
            acc = __builtin_amdgcn_mfma_f32_16x16x32_bf16(k1, aq1, acc, 0, 0, 0);
            sc[i * 2 + h] = acc;
        }

    // ---- scale + mask from bits ----
#pragma unroll
    for (int t = 0; t < 8; ++t)
#pragma unroll
        for (int r = 0; r < 4; ++r)
            sc[t][r] = ((mbits >> (t * 4 + r)) & 1u) ? 1e-9f : sc[t][r] * 0.125f;

    // ---- row max ----
    float rmax = sc[0][0];
#pragma unroll
    for (int t = 0; t < 8; ++t)
#pragma unroll
        for (int r = 0; r < 4; ++r) rmax = fmaxf(rmax, sc[t][r]);
    rmax = fmaxf(rmax, __shfl_xor(rmax, 16));
    rmax = fmaxf(rmax, __shfl_xor(rmax, 32));
    __syncthreads();
    if (lane < 16) red[qrow * 8 + wc] = rmax;
    __syncthreads();
    {
        const f32x4 a = *(const f32x4*)(red + qrow * 8);
        const f32x4 bq = *(const f32x4*)(red + qrow * 8 + 4);
        rmax = fmaxf(fmaxf(fmaxf(a[0], a[1]), fmaxf(a[2], a[3])),
                     fmaxf(fmaxf(bq[0], bq[1]), fmaxf(bq[2], bq[3])));
    }

    // ---- exp + row sum ----
    float rsum = 0.f;
#pragma unroll
    for (int t = 0; t < 8; ++t)
#pragma unroll
        for (int r = 0; r < 4; ++r) {
            const float p = __expf(sc[t][r] - rmax);
            sc[t][r] = p;
            rsum += p;
        }
    rsum += __shfl_xor(rsum, 16);
    rsum += __shfl_xor(rsum, 32);
    __syncthreads();
    if (lane < 16) red[qrow * 8 + wc] = rsum;
    __syncthreads();
    float rinv;
    {
        const f32x4 a = *(const f32x4*)(red + qrow * 8);
        const f32x4 bq = *(const f32x4*)(red + qrow * 8 + 4);
        rinv = 1.0f / ((a[0] + a[1] + a[2] + a[3]) + (bq[0] + bq[1] + bq[2] + bq[3]));
    }
#pragma unroll
    for (int t = 0; t < 8; ++t)
#pragma unroll
        for (int r = 0; r < 4; ++r) sc[t][r] *= rinv;

    // ---- attn stores: issue all now, drain under phase 2 ----
    {
        float* arow = Ap + (size_t)qrow * S_LEN + wc * 32 + lg * 4;
#pragma unroll
        for (int i = 0; i < 4; ++i) {
            *(f32x4*)(arow + i * 256)      = sc[i * 2 + 0];
            *(f32x4*)(arow + i * 256 + 16) = sc[i * 2 + 1];
        }
    }

    // ---- P -> bf16 A-fragments (frees sc) ----
    bf16x8 paf[4];
#pragma unroll
    for (int i = 0; i < 4; ++i) {
        union { bf16x8 v; unsigned short e[8]; } pa;
#pragma unroll
        for (int r = 0; r < 4; ++r) {
            pa.e[r]     = bf16u(sc[i * 2 + 0][r]);
            pa.e[4 + r] = bf16u(sc[i * 2 + 1][r]);
        }
        paf[i] = pa.v;
    }

    // ---- Phase 2: context = P·V over 4 tiles of 256 kv rows ----
    f32x4 co[4];
#pragma unroll
    for (int m = 0; m < 4; ++m) co[m] = (f32x4){0.f, 0.f, 0.f, 0.f};

    for (int i = 0; i < 4; ++i) {
        __syncthreads();   // prior iter frag reads (and red reads, i=0) done
        const float* vsrc = Vp + (size_t)i * (256 * DQ);
#pragma unroll
        for (int j = 0; j < 4; ++j) {
            const int f = (j * 1024 + tid) * 4;
            const float4 v4 = *(const float4*)(vsrc + f);
            const int k = f >> 6, d = f & 63;
            Vt[(d + 0) * VSTR + k] = bf16u(v4.x);
            Vt[(d + 1) * VSTR + k] = bf16u(v4.y);
            Vt[(d + 2) * VSTR + k] = bf16u(v4.z);
            Vt[(d + 3) * VSTR + k] = bf16u(v4.w);
        }
        __syncthreads();
#pragma unroll
        for (int m = 0; m < 4; ++m) {
            const bf16x8 bv = ld_frag2(Vt + (size_t)(m * 16 + l15) * VSTR + wc * 32 + lg * 4);
            co[m] = __builtin_amdgcn_mfma_f32_16x16x32_bf16(paf[i], bv, co[m], 0, 0, 0);
        }
    }

    // ---- ordered deterministic cross-wave reduce (8 wc strips) ----
    __syncthreads();   // last Vt reads done before Cx (aliased) writes
#pragma unroll
    for (int w = 0; w < 8; ++w) {
        if (wc == w) {
#pragma unroll
            for (int m = 0; m < 4; ++m)
#pragma unroll
                for (int r = 0; r < 4; ++r) {
                    float* p = Cx + (size_t)(wr * 16 + lg * 4 + r) * CSTR + m * 16 + l15;
                    if (w == 0) *p = co[m][r];
                    else        *p += co[m][r];
                }
        }
        __syncthreads();
    }

    // ---- coalesced context write ----
    if (tid < 512) {
        const int row = tid >> 4, col = (tid & 15) * 4;
        *(f32x4*)(Op + (size_t)row * DQ + col) = *(const f32x4*)(Cx + (size_t)row * CSTR + col);
    }
}

extern "C" void kernel_launch(void* const* d_in, const int* in_sizes, int n_in,
                              void* d_out, int out_size, void* d_ws, size_t ws_size,
                              hipStream_t stream) {
    const float* Q = (const float*)d_in[0];
    const float* K = (const float*)d_in[1];
    const float* V = (const float*)d_in[2];
    const int*   M = (const int*)d_in[3];
    float* ctx  = (float*)d_out;
    float* attn = ctx + (size_t)8 * 16 * 1024 * 64;   // context first, then attn
    attn_fused<<<dim3(4096), dim3(1024), 0, stream>>>(Q, K, V, M, ctx, attn);
}